// Round 14
// baseline (446.637 us; speedup 1.0000x reference)
//
#include <hip/hip_runtime.h>

#define F128 128
#define EPSV 1e-12f

typedef short bf16x8 __attribute__((ext_vector_type(8)));
typedef float f32x4 __attribute__((ext_vector_type(4)));
typedef unsigned short u16x4 __attribute__((ext_vector_type(4)));

static __device__ __forceinline__ unsigned short f2bf(float f) {
  unsigned u = __float_as_uint(f);
  u += 0x7FFF + ((u >> 16) & 1);  // round to nearest even
  return (unsigned short)(u >> 16);
}
static __device__ __forceinline__ float bf2f(unsigned short b) {
  return __uint_as_float(((unsigned)b) << 16);
}

// ---------------- CSR build ----------------
__global__ void hist_kernel(const int* __restrict__ row, int* __restrict__ counts, int E) {
  int i = blockIdx.x * blockDim.x + threadIdx.x;
  int stride = gridDim.x * blockDim.x;
  for (; i < E; i += stride) atomicAdd(&counts[row[i]], 1);
}

__global__ __launch_bounds__(1024) void scan_local_kernel(const int* __restrict__ counts,
                                                          int* __restrict__ tmp,
                                                          int* __restrict__ partials, int n) {
  __shared__ int buf[1024];
  int t = threadIdx.x;
  int i = blockIdx.x * 1024 + t;
  int v = (i < n) ? counts[i] : 0;
  buf[t] = v;
  __syncthreads();
  for (int off = 1; off < 1024; off <<= 1) {
    int add = (t >= off) ? buf[t - off] : 0;
    __syncthreads();
    buf[t] += add;
    __syncthreads();
  }
  if (i < n) tmp[i] = buf[t];
  if (t == 1023) partials[blockIdx.x] = buf[1023];
}

__global__ __launch_bounds__(256) void scan_part_kernel(const int* __restrict__ partials,
                                                        int* __restrict__ part_excl, int nblk) {
  __shared__ int buf[256];
  int t = threadIdx.x;
  int v = (t < nblk) ? partials[t] : 0;
  buf[t] = v;
  __syncthreads();
  for (int off = 1; off < 256; off <<= 1) {
    int add = (t >= off) ? buf[t - off] : 0;
    __syncthreads();
    buf[t] += add;
    __syncthreads();
  }
  if (t < nblk) part_excl[t] = buf[t] - v;
}

__global__ __launch_bounds__(1024) void scan_fin_kernel(const int* __restrict__ tmp,
                                                        const int* __restrict__ part_excl,
                                                        const int* __restrict__ counts,
                                                        int* __restrict__ row_ptr,
                                                        int* __restrict__ fill, int n) {
  int t = threadIdx.x;
  int i = blockIdx.x * 1024 + t;
  if (i < n) {
    int incl = tmp[i] + part_excl[blockIdx.x];
    row_ptr[i + 1] = incl;
    fill[i] = incl - counts[i];  // exclusive prefix
  }
  if (i == 0) row_ptr[0] = 0;
}

// XCD-partitioned scatter (round-10 proven form)
__global__ void scatter_kernel(const int* __restrict__ row, const int* __restrict__ col,
                               const float* __restrict__ val, int* __restrict__ fill,
                               int2* __restrict__ edges, int E, int N) {
  int part = blockIdx.x & 7;
  int g = blockIdx.x >> 3;
  int stride = (gridDim.x >> 3) * blockDim.x;
  int lo = (int)(((long long)N * part) >> 3);
  int hi = (int)(((long long)N * (part + 1)) >> 3);
  for (int i = g * blockDim.x + threadIdx.x; i < E; i += stride) {
    int r = row[i];
    if (r >= lo && r < hi) {
      int pos = atomicAdd(&fill[r], 1);
      edges[pos] = make_int2(col[i], __float_as_int(val[i]));
    }
  }
}

// ---------------- generic column reduce: out[f] = sum_p part[p][f] (128-wide slabs) --------
__global__ __launch_bounds__(256) void reduce_cols_kernel(const float* __restrict__ part,
                                                          float* __restrict__ out, int P) {
  __shared__ float red[256];
  int f = blockIdx.x;
  int t = threadIdx.x;
  float s = 0.f;
  for (int p = t; p < P; p += 256) s += part[(size_t)p * F128 + f];
  red[t] = s;
  __syncthreads();
  for (int off = 128; off > 0; off >>= 1) {
    if (t < off) red[t] += red[t + off];
    __syncthreads();
  }
  if (t == 0) out[f] = red[0];
}

// ---------------- quarter-aware reduce for alpha: part is [npairs*8][32] compact ----------
__global__ __launch_bounds__(256) void reduce_quarter_kernel(const float* __restrict__ part,
                                                             float* __restrict__ out, int npairs) {
  __shared__ float red[256];
  int f = blockIdx.x;          // 0..127
  int q = f >> 5, fi = f & 31;
  int t = threadIdx.x;
  int nb = npairs * 2;         // blocks per quarter
  float s = 0.f;
  for (int j = t; j < nb; j += 256) {
    int g = j >> 1, sub = j & 1;
    int b = g * 8 + 2 * q + sub;
    s += part[(size_t)b * 32 + fi];
  }
  red[t] = s;
  __syncthreads();
  for (int off = 128; off > 0; off >>= 1) {
    if (t < off) red[t] += red[t + off];
    __syncthreads();
  }
  if (t == 0) out[f] = red[0];
}

// ---------------- SpMV, feature-quarter partitioned across XCDs ----------------
// Block b: XCD slot x=b%8 -> quarter q=x>>1 (32 features = one 64B line per row; 3.2MB
// gather footprint fits a 4MiB XCD L2). 16-lane group per edge, 4 edges/wave-instr,
// unroll-4 => 4 independent gathers in flight per lane (round-10 MLP depth).
__global__ __launch_bounds__(256) void spmv_dot_kernel(const int* __restrict__ row_ptr,
                                                       const int2* __restrict__ edges,
                                                       const unsigned short* __restrict__ ubf,
                                                       const float* __restrict__ raw, float eps,
                                                       unsigned short* __restrict__ wbf,
                                                       float* __restrict__ dot_part,
                                                       int N, int npairs) {
  __shared__ float part[4][32];
  int b = blockIdx.x;
  int x = b & 7, g = b >> 3;
  int q = x >> 1, sub = x & 1;
  int j0 = g * 2 + sub;
  int jstride = npairs * 2;
  int ntiles = (N + 15) / 16;
  int wv = threadIdx.x >> 6, lane = threadIdx.x & 63;
  int slot = lane >> 4, li = lane & 15;
  int foff = q * 32 + li * 2;
  float rin0 = rsqrtf(fmaxf(raw[foff + 0], eps));
  float rin1 = rsqrtf(fmaxf(raw[foff + 1], eps));
  float dx = 0.f, dy = 0.f;
  for (int tile = j0; tile < ntiles; tile += jstride) {
    int row0 = tile * 16 + wv * 4;
#pragma unroll 1
    for (int r = 0; r < 4; ++r) {
      int wid = row0 + r;
      if (wid >= N) break;
      int beg = row_ptr[wid], end = row_ptr[wid + 1];
      float a0x = 0.f, a0y = 0.f, a1x = 0.f, a1y = 0.f;
      float a2x = 0.f, a2y = 0.f, a3x = 0.f, a3y = 0.f;
      int e = beg;
      for (; e + 16 <= end; e += 16) {
        int2 e0 = edges[e + 0 + slot];
        int2 e1 = edges[e + 4 + slot];
        int2 e2 = edges[e + 8 + slot];
        int2 e3 = edges[e + 12 + slot];
        unsigned g0 = *(const unsigned*)&ubf[(size_t)e0.x * F128 + foff];
        unsigned g1 = *(const unsigned*)&ubf[(size_t)e1.x * F128 + foff];
        unsigned g2 = *(const unsigned*)&ubf[(size_t)e2.x * F128 + foff];
        unsigned g3 = *(const unsigned*)&ubf[(size_t)e3.x * F128 + foff];
        float s0 = __int_as_float(e0.y), s1 = __int_as_float(e1.y);
        float s2 = __int_as_float(e2.y), s3 = __int_as_float(e3.y);
        a0x += s0 * bf2f((unsigned short)(g0 & 0xffffu));
        a0y += s0 * bf2f((unsigned short)(g0 >> 16));
        a1x += s1 * bf2f((unsigned short)(g1 & 0xffffu));
        a1y += s1 * bf2f((unsigned short)(g1 >> 16));
        a2x += s2 * bf2f((unsigned short)(g2 & 0xffffu));
        a2y += s2 * bf2f((unsigned short)(g2 >> 16));
        a3x += s3 * bf2f((unsigned short)(g3 & 0xffffu));
        a3y += s3 * bf2f((unsigned short)(g3 >> 16));
      }
      for (; e < end; e += 4) {
        bool ok = (e + slot) < end;
        int2 ee = ok ? edges[e + slot] : make_int2(0, 0);
        unsigned gg = *(const unsigned*)&ubf[(size_t)ee.x * F128 + foff];
        float ss = __int_as_float(ee.y);
        a0x += ss * bf2f((unsigned short)(gg & 0xffffu));
        a0y += ss * bf2f((unsigned short)(gg >> 16));
      }
      float accx = (a0x + a1x) + (a2x + a3x);
      float accy = (a0y + a1y) + (a2y + a3y);
      // combine the 4 edge-slots (16-lane groups)
      accx += __shfl_xor(accx, 16);
      accy += __shfl_xor(accy, 16);
      accx += __shfl_xor(accx, 32);
      accy += __shfl_xor(accy, 32);
      if (slot == 0) {
        float ox = accx * rin0;
        float oy = accy * rin1;
        unsigned pk = ((unsigned)f2bf(oy) << 16) | (unsigned)f2bf(ox);
        *(unsigned*)&wbf[(size_t)wid * F128 + foff] = pk;
        unsigned ub = *(const unsigned*)&ubf[(size_t)wid * F128 + foff];
        dx += ox * bf2f((unsigned short)(ub & 0xffffu)) * rin0;
        dy += oy * bf2f((unsigned short)(ub >> 16)) * rin1;
      }
    }
  }
  if (slot == 0) {
    part[wv][li * 2 + 0] = dx;
    part[wv][li * 2 + 1] = dy;
  }
  __syncthreads();
  if (threadIdx.x < 32) {
    float s = part[0][threadIdx.x] + part[1][threadIdx.x] +
              part[2][threadIdx.x] + part[3][threadIdx.x];
    dot_part[(size_t)b * 32 + threadIdx.x] = s;
  }
}

// ---------------- column sumsq partials + bf16 shadow of x ----------------
__global__ __launch_bounds__(256) void colsq_kernel(const float* __restrict__ a,
                                                    unsigned short* __restrict__ abf,
                                                    float* __restrict__ part, int nrows) {
  int t = threadIdx.x;
  int f0 = (t & 31) * 4;
  int rslot = blockIdx.x * 8 + (t >> 5);
  int rstride = gridDim.x * 8;
  float4 acc = make_float4(0.f, 0.f, 0.f, 0.f);
  for (int r = rslot; r < nrows; r += rstride) {
    size_t idx = (size_t)r * F128 + f0;
    float4 av = *(const float4*)&a[idx];
    ushort4 bv;
    bv.x = f2bf(av.x); bv.y = f2bf(av.y); bv.z = f2bf(av.z); bv.w = f2bf(av.w);
    *(ushort4*)&abf[idx] = bv;
    acc.x += av.x * av.x; acc.y += av.y * av.y;
    acc.z += av.z * av.z; acc.w += av.w * av.w;
  }
  __shared__ float4 red[256];
  red[t] = acc;
  __syncthreads();
  if (t < 32) {
    float4 s = red[t];
#pragma unroll
    for (int j = 1; j < 8; ++j) {
      float4 o = red[t + 32 * j];
      s.x += o.x; s.y += o.y; s.z += o.z; s.w += o.w;
    }
    *(float4*)&part[(size_t)blockIdx.x * F128 + t * 4] = s;
  }
}

// ---------------- u_new = w - alpha*(up*c) - beta*(up2*c2); all-bf16 streams + partials ----
template <int HAS_PREV>
__global__ __launch_bounds__(256) void newv_kernel(const unsigned short* __restrict__ wbf,
                                                   unsigned short* __restrict__ outbf,
                                                   const unsigned short* __restrict__ upbf,
                                                   const unsigned short* __restrict__ up2bf,
                                                   const float* __restrict__ alpha,
                                                   const float* __restrict__ prev_raw, float prev_eps,
                                                   const float* __restrict__ prev2_raw, float prev2_eps,
                                                   float* __restrict__ bsq_part, int nrows) {
  int t = threadIdx.x;
  int f0 = (t & 31) * 4;
  int rslot = blockIdx.x * 8 + (t >> 5);
  int rstride = gridDim.x * 8;
  float4 a = *(const float4*)&alpha[f0];
  float4 pr = *(const float4*)&prev_raw[f0];
  float4 cp;
  cp.x = rsqrtf(fmaxf(pr.x, prev_eps)); cp.y = rsqrtf(fmaxf(pr.y, prev_eps));
  cp.z = rsqrtf(fmaxf(pr.z, prev_eps)); cp.w = rsqrtf(fmaxf(pr.w, prev_eps));
  float4 ac;
  ac.x = a.x * cp.x; ac.y = a.y * cp.y; ac.z = a.z * cp.z; ac.w = a.w * cp.w;
  float4 g = make_float4(0.f, 0.f, 0.f, 0.f);
  if (HAS_PREV) {
    float4 p2 = *(const float4*)&prev2_raw[f0];
    g.x = sqrtf(pr.x) * rsqrtf(fmaxf(p2.x, prev2_eps));
    g.y = sqrtf(pr.y) * rsqrtf(fmaxf(p2.y, prev2_eps));
    g.z = sqrtf(pr.z) * rsqrtf(fmaxf(p2.z, prev2_eps));
    g.w = sqrtf(pr.w) * rsqrtf(fmaxf(p2.w, prev2_eps));
  }
  float4 acc = make_float4(0.f, 0.f, 0.f, 0.f);
  for (int r = rslot; r < nrows; r += rstride) {
    size_t idx = (size_t)r * F128 + f0;
    ushort4 wb = *(const ushort4*)&wbf[idx];
    float4 wv;
    wv.x = bf2f(wb.x); wv.y = bf2f(wb.y); wv.z = bf2f(wb.z); wv.w = bf2f(wb.w);
    ushort4 pb = *(const ushort4*)&upbf[idx];
    wv.x -= ac.x * bf2f(pb.x);
    wv.y -= ac.y * bf2f(pb.y);
    wv.z -= ac.z * bf2f(pb.z);
    wv.w -= ac.w * bf2f(pb.w);
    if (HAS_PREV) {
      ushort4 qb = *(const ushort4*)&up2bf[idx];
      wv.x -= g.x * bf2f(qb.x);
      wv.y -= g.y * bf2f(qb.y);
      wv.z -= g.z * bf2f(qb.z);
      wv.w -= g.w * bf2f(qb.w);
    }
    u16x4 ob;
    ob.x = f2bf(wv.x); ob.y = f2bf(wv.y); ob.z = f2bf(wv.z); ob.w = f2bf(wv.w);
    *(u16x4*)&outbf[idx] = ob;
    acc.x += wv.x * wv.x; acc.y += wv.y * wv.y;
    acc.z += wv.z * wv.z; acc.w += wv.w * wv.w;
  }
  __shared__ float4 red[256];
  red[t] = acc;
  __syncthreads();
  if (t < 32) {
    float4 s = red[t];
#pragma unroll
    for (int j = 1; j < 8; ++j) {
      float4 o = red[t + 32 * j];
      s.x += o.x; s.y += o.y; s.z += o.z; s.w += o.w;
    }
    *(float4*)&bsq_part[(size_t)blockIdx.x * F128 + t * 4] = s;
  }
}

// ---------------- W prep: fold per-column scale into W, emit bf16 MFMA B-frag layout ----------
__global__ void wprep_kernel(const float* __restrict__ weights,
                             const float* __restrict__ norms,
                             const float* __restrict__ betasq,
                             unsigned short* __restrict__ wfrag, int total) {
  int t = blockIdx.x * blockDim.x + threadIdx.x;
  if (t >= total) return;
  int k = t >> 14;          // F128*F128 = 16384
  int f = (t >> 7) & 127;
  int d = t & 127;
  float c = (k == 0) ? rsqrtf(fmaxf(norms[f], EPSV)) : rsqrtf(betasq[(k - 1) * F128 + f]);
  float val = weights[t] * c;
  int Kidx = k * F128 + f;
  int kstep = Kidx >> 5, kin = Kidx & 31;
  int lane = ((kin >> 3) << 4) | (d & 15);
  int ct = d >> 4, j = kin & 7;
  wfrag[(((kstep * 8 + ct) * 64 + lane) << 3) | j] = f2bf(val);
}

// ---------------- fused MFMA GEMM: out = relu(sum_k Vk @ Wk), A read from bf16 shadows ------
__global__ __launch_bounds__(256) void mfma_gemm_kernel(float* __restrict__ out,
                                                        const unsigned short* __restrict__ xbf,
                                                        const unsigned short* __restrict__ ubfs,
                                                        size_t nf,
                                                        const unsigned short* __restrict__ wfrag,
                                                        int N, int K) {
  int wv = threadIdx.x >> 6, lane = threadIdx.x & 63;
  int n0 = blockIdx.x * 64 + wv * 16;
  if (n0 >= N) return;
  int rrow = n0 + (lane & 15);
  if (rrow >= N) rrow = N - 1;  // clamp: loads safe, stores guarded
  int khalf = lane >> 4;        // 0..3
  f32x4 acc[8];
#pragma unroll
  for (int i = 0; i < 8; ++i) acc[i] = (f32x4){0.f, 0.f, 0.f, 0.f};
  for (int k = 0; k < K; ++k) {
    const unsigned short* Uk = (k == 0) ? xbf : (ubfs + (size_t)(k - 1) * nf);
    const unsigned short* arow = Uk + (size_t)rrow * F128 + khalf * 8;
#pragma unroll
    for (int kk = 0; kk < 4; ++kk) {
      bf16x8 af = *(const bf16x8*)(arow + kk * 32);
      int kstep = k * 4 + kk;
      const unsigned short* bbase = wfrag + (((kstep * 8) * 64 + lane) << 3);
#pragma unroll
      for (int ct = 0; ct < 8; ++ct) {
        bf16x8 bfr = *(const bf16x8*)(bbase + (ct << 9));  // ct*64*8
        acc[ct] = __builtin_amdgcn_mfma_f32_16x16x32_bf16(af, bfr, acc[ct], 0, 0, 0);
      }
    }
  }
#pragma unroll
  for (int ct = 0; ct < 8; ++ct) {
#pragma unroll
    for (int j = 0; j < 4; ++j) {
      int r = n0 + khalf * 4 + j;
      if (r < N) out[(size_t)r * F128 + ct * 16 + (lane & 15)] = fmaxf(acc[ct][j], 0.f);
    }
  }
}

extern "C" void kernel_launch(void* const* d_in, const int* in_sizes, int n_in,
                              void* d_out, int out_size, void* d_ws, size_t ws_size,
                              hipStream_t stream) {
  const float* x = (const float*)d_in[0];
  const float* edge_vals = (const float*)d_in[1];
  const float* weights = (const float*)d_in[2];
  const int* edge_row = (const int*)d_in[3];
  const int* edge_col = (const int*)d_in[4];

  const int N = in_sizes[0] / F128;
  const int E = in_sizes[1];
  const int K = in_sizes[2] / (F128 * F128);
  float* out = (float*)d_out;

  size_t nf = (size_t)N * F128;
  const int NPAIRS = 512;               // spmv grid = NPAIRS*8 = 4096 blocks
  const int SPMV_GRID = NPAIRS * 8;
  const int RB = 2048;                  // blocks for streaming column-reduce kernels

  unsigned short* wbf = (unsigned short*)d_ws;          // bf16 spmv-output buffer
  unsigned short* xbf = wbf + nf;                       // bf16 shadow of x
  unsigned short* ubfs = xbf + nf;                      // (K-1) bf16 Lanczos shadows
  unsigned short* wfrag = ubfs + (size_t)(K - 1) * nf;
  int wtotal = K * F128 * F128;
  int* row_ptr = (int*)(wfrag + wtotal);
  int* fill = row_ptr + (N + 2);
  int* counts = fill + N;
  int* tmp = counts + N;
  int* partials = tmp + N;        // 256
  int* part_excl = partials + 256;
  int2* edges = (int2*)(part_excl + 256);
  float* dot_part = (float*)(edges + E);                 // SPMV_GRID * 32 (compact)
  float* col_part = dot_part + (size_t)SPMV_GRID * 32;   // RB * 128
  float* norms = col_part + (size_t)RB * F128;           // 128
  float* alpha = norms + F128;                           // 8 slots of 128
  float* betasq = alpha + 8 * F128;                      // 8 slots of 128

  hipMemsetAsync(counts, 0, (size_t)N * sizeof(int), stream);

  // CSR build
  int nblk = (N + 1023) / 1024;  // must be <=256
  hist_kernel<<<1024, 256, 0, stream>>>(edge_row, counts, E);
  scan_local_kernel<<<nblk, 1024, 0, stream>>>(counts, tmp, partials, N);
  scan_part_kernel<<<1, 256, 0, stream>>>(partials, part_excl, nblk);
  scan_fin_kernel<<<nblk, 1024, 0, stream>>>(tmp, part_excl, counts, row_ptr, fill, N);
  scatter_kernel<<<2048, 256, 0, stream>>>(edge_row, edge_col, edge_vals, fill, edges, E, N);

  // column sumsq of x + bf16 shadow of x
  colsq_kernel<<<RB, 256, 0, stream>>>(x, xbf, col_part, N);
  reduce_cols_kernel<<<F128, 256, 0, stream>>>(col_part, norms, RB);

  const unsigned short* ubf_prev = xbf;
  const unsigned short* ubf_prev2 = nullptr;
  const float* praw = norms;
  float peps = EPSV;
  const float* p2raw = nullptr;
  float p2eps = 0.f;
  for (int s = 1; s < K; ++s) {
    unsigned short* ubf_out = ubfs + (size_t)(s - 1) * nf;
    float* alph = alpha + (size_t)(s - 1) * F128;
    float* bsq = betasq + (size_t)(s - 1) * F128;

    spmv_dot_kernel<<<SPMV_GRID, 256, 0, stream>>>(row_ptr, edges, ubf_prev, praw, peps,
                                                   wbf, dot_part, N, NPAIRS);
    reduce_quarter_kernel<<<F128, 256, 0, stream>>>(dot_part, alph, NPAIRS);
    if (s == 1)
      newv_kernel<0><<<RB, 256, 0, stream>>>(wbf, ubf_out, ubf_prev, nullptr, alph, praw, peps,
                                             nullptr, 0.f, col_part, N);
    else
      newv_kernel<1><<<RB, 256, 0, stream>>>(wbf, ubf_out, ubf_prev, ubf_prev2, alph, praw, peps,
                                             p2raw, p2eps, col_part, N);
    reduce_cols_kernel<<<F128, 256, 0, stream>>>(col_part, bsq, RB);

    ubf_prev2 = ubf_prev; p2raw = praw; p2eps = peps;
    ubf_prev = ubf_out;   praw = bsq;   peps = 0.f;
  }

  // fold scales into W (bf16, MFMA frag layout), then one fused MFMA GEMM + relu
  wprep_kernel<<<(wtotal + 255) / 256, 256, 0, stream>>>(weights, norms, betasq, wfrag, wtotal);
  mfma_gemm_kernel<<<(N + 63) / 64, 256, 0, stream>>>(out, xbf, ubfs, nf, wfrag, N, K);
}

// Round 15
// 313.208 us; speedup vs baseline: 1.4260x; 1.4260x over previous
//
#include <hip/hip_runtime.h>

#define F128 128
#define EPSV 1e-12f

typedef short bf16x8 __attribute__((ext_vector_type(8)));
typedef float f32x4 __attribute__((ext_vector_type(4)));
typedef unsigned short u16x4 __attribute__((ext_vector_type(4)));

static __device__ __forceinline__ unsigned short f2bf(float f) {
  unsigned u = __float_as_uint(f);
  u += 0x7FFF + ((u >> 16) & 1);  // round to nearest even
  return (unsigned short)(u >> 16);
}
static __device__ __forceinline__ float bf2f(unsigned short b) {
  return __uint_as_float(((unsigned)b) << 16);
}

// ---------------- CSR build ----------------
__global__ void hist_kernel(const int* __restrict__ row, int* __restrict__ counts, int E) {
  int i = blockIdx.x * blockDim.x + threadIdx.x;
  int stride = gridDim.x * blockDim.x;
  for (; i < E; i += stride) atomicAdd(&counts[row[i]], 1);
}

__global__ __launch_bounds__(1024) void scan_local_kernel(const int* __restrict__ counts,
                                                          int* __restrict__ tmp,
                                                          int* __restrict__ partials, int n) {
  __shared__ int buf[1024];
  int t = threadIdx.x;
  int i = blockIdx.x * 1024 + t;
  int v = (i < n) ? counts[i] : 0;
  buf[t] = v;
  __syncthreads();
  for (int off = 1; off < 1024; off <<= 1) {
    int add = (t >= off) ? buf[t - off] : 0;
    __syncthreads();
    buf[t] += add;
    __syncthreads();
  }
  if (i < n) tmp[i] = buf[t];
  if (t == 1023) partials[blockIdx.x] = buf[1023];
}

__global__ __launch_bounds__(256) void scan_part_kernel(const int* __restrict__ partials,
                                                        int* __restrict__ part_excl, int nblk) {
  __shared__ int buf[256];
  int t = threadIdx.x;
  int v = (t < nblk) ? partials[t] : 0;
  buf[t] = v;
  __syncthreads();
  for (int off = 1; off < 256; off <<= 1) {
    int add = (t >= off) ? buf[t - off] : 0;
    __syncthreads();
    buf[t] += add;
    __syncthreads();
  }
  if (t < nblk) part_excl[t] = buf[t] - v;
}

__global__ __launch_bounds__(1024) void scan_fin_kernel(const int* __restrict__ tmp,
                                                        const int* __restrict__ part_excl,
                                                        const int* __restrict__ counts,
                                                        int* __restrict__ row_ptr,
                                                        int* __restrict__ fill, int n) {
  int t = threadIdx.x;
  int i = blockIdx.x * 1024 + t;
  if (i < n) {
    int incl = tmp[i] + part_excl[blockIdx.x];
    row_ptr[i + 1] = incl;
    fill[i] = incl - counts[i];  // exclusive prefix
  }
  if (i == 0) row_ptr[0] = 0;
}

// XCD-partitioned scatter: blocks with (blockIdx&7)==p handle only rows in partition p.
__global__ void scatter_kernel(const int* __restrict__ row, const int* __restrict__ col,
                               const float* __restrict__ val, int* __restrict__ fill,
                               int2* __restrict__ edges, int E, int N) {
  int part = blockIdx.x & 7;
  int g = blockIdx.x >> 3;
  int stride = (gridDim.x >> 3) * blockDim.x;
  int lo = (int)(((long long)N * part) >> 3);
  int hi = (int)(((long long)N * (part + 1)) >> 3);
  for (int i = g * blockDim.x + threadIdx.x; i < E; i += stride) {
    int r = row[i];
    if (r >= lo && r < hi) {
      int pos = atomicAdd(&fill[r], 1);
      edges[pos] = make_int2(col[i], __float_as_int(val[i]));
    }
  }
}

// ---------------- generic column reduce: out[f] = sum_p part[p][f] ----------------
__global__ __launch_bounds__(256) void reduce_cols_kernel(const float* __restrict__ part,
                                                          float* __restrict__ out, int P) {
  __shared__ float red[256];
  int f = blockIdx.x;
  int t = threadIdx.x;
  float s = 0.f;
  for (int p = t; p < P; p += 256) s += part[(size_t)p * F128 + f];
  red[t] = s;
  __syncthreads();
  for (int off = 128; off > 0; off >>= 1) {
    if (t < off) red[t] += red[t + off];
    __syncthreads();
  }
  if (t == 0) out[f] = red[0];
}

// ---------------- SpMV (bf16 gather, 4-deep MLP, 4 rows/wave) + fused dot partials ----------
__global__ __launch_bounds__(256) void spmv_dot_kernel(const int* __restrict__ row_ptr,
                                                       const int2* __restrict__ edges,
                                                       const unsigned short* __restrict__ ubf,
                                                       const float* __restrict__ raw, float eps,
                                                       unsigned short* __restrict__ wbf,
                                                       float* __restrict__ dot_part, int N) {
  __shared__ float part[4][F128];
  int wv = threadIdx.x >> 6, lane = threadIdx.x & 63;
  int row0 = (blockIdx.x * 4 + wv) * 4;  // 4 rows per wave, 16 per block
  float rin0 = rsqrtf(fmaxf(raw[lane * 2 + 0], eps));
  float rin1 = rsqrtf(fmaxf(raw[lane * 2 + 1], eps));
  float dx = 0.f, dy = 0.f;
#pragma unroll 1
  for (int r = 0; r < 4; ++r) {
    int wid = row0 + r;
    if (wid >= N) break;
    int beg = row_ptr[wid], end = row_ptr[wid + 1];
    float ax0 = 0.f, ay0 = 0.f, ax1 = 0.f, ay1 = 0.f;
    float ax2 = 0.f, ay2 = 0.f, ax3 = 0.f, ay3 = 0.f;
    int e = beg;
    for (; e + 4 <= end; e += 4) {
      int eu = __builtin_amdgcn_readfirstlane(e);  // wave-uniform -> scalar loads
      int2 e0 = edges[eu + 0];
      int2 e1 = edges[eu + 1];
      int2 e2 = edges[eu + 2];
      int2 e3 = edges[eu + 3];
      unsigned b0 = *(const unsigned*)&ubf[(size_t)e0.x * F128 + lane * 2];
      unsigned b1 = *(const unsigned*)&ubf[(size_t)e1.x * F128 + lane * 2];
      unsigned b2 = *(const unsigned*)&ubf[(size_t)e2.x * F128 + lane * 2];
      unsigned b3 = *(const unsigned*)&ubf[(size_t)e3.x * F128 + lane * 2];
      float s0 = __int_as_float(e0.y), s1 = __int_as_float(e1.y);
      float s2 = __int_as_float(e2.y), s3 = __int_as_float(e3.y);
      ax0 += s0 * __uint_as_float(b0 << 16);
      ay0 += s0 * __uint_as_float(b0 & 0xffff0000u);
      ax1 += s1 * __uint_as_float(b1 << 16);
      ay1 += s1 * __uint_as_float(b1 & 0xffff0000u);
      ax2 += s2 * __uint_as_float(b2 << 16);
      ay2 += s2 * __uint_as_float(b2 & 0xffff0000u);
      ax3 += s3 * __uint_as_float(b3 << 16);
      ay3 += s3 * __uint_as_float(b3 & 0xffff0000u);
    }
    for (; e < end; ++e) {
      int eu = __builtin_amdgcn_readfirstlane(e);
      int2 ee = edges[eu];
      unsigned bb = *(const unsigned*)&ubf[(size_t)ee.x * F128 + lane * 2];
      float ss = __int_as_float(ee.y);
      ax0 += ss * __uint_as_float(bb << 16);
      ay0 += ss * __uint_as_float(bb & 0xffff0000u);
    }
    float ox = ((ax0 + ax1) + (ax2 + ax3)) * rin0;
    float oy = ((ay0 + ay1) + (ay2 + ay3)) * rin1;
    unsigned packed = ((unsigned)f2bf(oy) << 16) | (unsigned)f2bf(ox);
    *(unsigned*)&wbf[(size_t)wid * F128 + lane * 2] = packed;
    unsigned ub = *(const unsigned*)&ubf[(size_t)wid * F128 + lane * 2];
    dx += ox * __uint_as_float(ub << 16) * rin0;
    dy += oy * __uint_as_float(ub & 0xffff0000u) * rin1;
  }
  part[wv][lane * 2 + 0] = dx;
  part[wv][lane * 2 + 1] = dy;
  __syncthreads();
  if (threadIdx.x < F128) {
    float s = part[0][threadIdx.x] + part[1][threadIdx.x] +
              part[2][threadIdx.x] + part[3][threadIdx.x];
    dot_part[(size_t)blockIdx.x * F128 + threadIdx.x] = s;
  }
}

// ---------------- column sumsq partials + bf16 shadow of x ----------------
__global__ __launch_bounds__(256) void colsq_kernel(const float* __restrict__ a,
                                                    unsigned short* __restrict__ abf,
                                                    float* __restrict__ part, int nrows) {
  int t = threadIdx.x;
  int f0 = (t & 31) * 4;
  int rslot = blockIdx.x * 8 + (t >> 5);
  int rstride = gridDim.x * 8;
  float4 acc = make_float4(0.f, 0.f, 0.f, 0.f);
  for (int r = rslot; r < nrows; r += rstride) {
    size_t idx = (size_t)r * F128 + f0;
    float4 av = *(const float4*)&a[idx];
    ushort4 bv;
    bv.x = f2bf(av.x); bv.y = f2bf(av.y); bv.z = f2bf(av.z); bv.w = f2bf(av.w);
    *(ushort4*)&abf[idx] = bv;
    acc.x += av.x * av.x; acc.y += av.y * av.y;
    acc.z += av.z * av.z; acc.w += av.w * av.w;
  }
  __shared__ float4 red[256];
  red[t] = acc;
  __syncthreads();
  if (t < 32) {
    float4 s = red[t];
#pragma unroll
    for (int j = 1; j < 8; ++j) {
      float4 o = red[t + 32 * j];
      s.x += o.x; s.y += o.y; s.z += o.z; s.w += o.w;
    }
    *(float4*)&part[(size_t)blockIdx.x * F128 + t * 4] = s;
  }
}

// ---------------- u_new = w - alpha*(up*c) - beta*(up2*c2); all-bf16 streams + partials ----
template <int HAS_PREV>
__global__ __launch_bounds__(256) void newv_kernel(const unsigned short* __restrict__ wbf,
                                                   unsigned short* __restrict__ outbf,
                                                   const unsigned short* __restrict__ upbf,
                                                   const unsigned short* __restrict__ up2bf,
                                                   const float* __restrict__ alpha,
                                                   const float* __restrict__ prev_raw, float prev_eps,
                                                   const float* __restrict__ prev2_raw, float prev2_eps,
                                                   float* __restrict__ bsq_part, int nrows) {
  int t = threadIdx.x;
  int f0 = (t & 31) * 4;
  int rslot = blockIdx.x * 8 + (t >> 5);
  int rstride = gridDim.x * 8;
  float4 a = *(const float4*)&alpha[f0];
  float4 pr = *(const float4*)&prev_raw[f0];
  float4 cp;
  cp.x = rsqrtf(fmaxf(pr.x, prev_eps)); cp.y = rsqrtf(fmaxf(pr.y, prev_eps));
  cp.z = rsqrtf(fmaxf(pr.z, prev_eps)); cp.w = rsqrtf(fmaxf(pr.w, prev_eps));
  float4 ac;
  ac.x = a.x * cp.x; ac.y = a.y * cp.y; ac.z = a.z * cp.z; ac.w = a.w * cp.w;
  float4 g = make_float4(0.f, 0.f, 0.f, 0.f);
  if (HAS_PREV) {
    float4 p2 = *(const float4*)&prev2_raw[f0];
    g.x = sqrtf(pr.x) * rsqrtf(fmaxf(p2.x, prev2_eps));
    g.y = sqrtf(pr.y) * rsqrtf(fmaxf(p2.y, prev2_eps));
    g.z = sqrtf(pr.z) * rsqrtf(fmaxf(p2.z, prev2_eps));
    g.w = sqrtf(pr.w) * rsqrtf(fmaxf(p2.w, prev2_eps));
  }
  float4 acc = make_float4(0.f, 0.f, 0.f, 0.f);
  for (int r = rslot; r < nrows; r += rstride) {
    size_t idx = (size_t)r * F128 + f0;
    ushort4 wb = *(const ushort4*)&wbf[idx];
    float4 wv;
    wv.x = bf2f(wb.x); wv.y = bf2f(wb.y); wv.z = bf2f(wb.z); wv.w = bf2f(wb.w);
    ushort4 pb = *(const ushort4*)&upbf[idx];
    wv.x -= ac.x * bf2f(pb.x);
    wv.y -= ac.y * bf2f(pb.y);
    wv.z -= ac.z * bf2f(pb.z);
    wv.w -= ac.w * bf2f(pb.w);
    if (HAS_PREV) {
      ushort4 qb = *(const ushort4*)&up2bf[idx];
      wv.x -= g.x * bf2f(qb.x);
      wv.y -= g.y * bf2f(qb.y);
      wv.z -= g.z * bf2f(qb.z);
      wv.w -= g.w * bf2f(qb.w);
    }
    u16x4 ob;
    ob.x = f2bf(wv.x); ob.y = f2bf(wv.y); ob.z = f2bf(wv.z); ob.w = f2bf(wv.w);
    *(u16x4*)&outbf[idx] = ob;
    acc.x += wv.x * wv.x; acc.y += wv.y * wv.y;
    acc.z += wv.z * wv.z; acc.w += wv.w * wv.w;
  }
  __shared__ float4 red[256];
  red[t] = acc;
  __syncthreads();
  if (t < 32) {
    float4 s = red[t];
#pragma unroll
    for (int j = 1; j < 8; ++j) {
      float4 o = red[t + 32 * j];
      s.x += o.x; s.y += o.y; s.z += o.z; s.w += o.w;
    }
    *(float4*)&bsq_part[(size_t)blockIdx.x * F128 + t * 4] = s;
  }
}

// ---------------- W prep: fold per-column scale into W, emit bf16 MFMA B-frag layout ----------
__global__ void wprep_kernel(const float* __restrict__ weights,
                             const float* __restrict__ norms,
                             const float* __restrict__ betasq,
                             unsigned short* __restrict__ wfrag, int total) {
  int t = blockIdx.x * blockDim.x + threadIdx.x;
  if (t >= total) return;
  int k = t >> 14;          // F128*F128 = 16384
  int f = (t >> 7) & 127;
  int d = t & 127;
  float c = (k == 0) ? rsqrtf(fmaxf(norms[f], EPSV)) : rsqrtf(betasq[(k - 1) * F128 + f]);
  float val = weights[t] * c;
  int Kidx = k * F128 + f;
  int kstep = Kidx >> 5, kin = Kidx & 31;
  int lane = ((kin >> 3) << 4) | (d & 15);
  int ct = d >> 4, j = kin & 7;
  wfrag[(((kstep * 8 + ct) * 64 + lane) << 3) | j] = f2bf(val);
}

// ---------------- fused MFMA GEMM: out = relu(sum_k Vk @ Wk), A read from bf16 shadows ------
__global__ __launch_bounds__(256) void mfma_gemm_kernel(float* __restrict__ out,
                                                        const unsigned short* __restrict__ xbf,
                                                        const unsigned short* __restrict__ ubfs,
                                                        size_t nf,
                                                        const unsigned short* __restrict__ wfrag,
                                                        int N, int K) {
  int wv = threadIdx.x >> 6, lane = threadIdx.x & 63;
  int n0 = blockIdx.x * 64 + wv * 16;
  if (n0 >= N) return;
  int rrow = n0 + (lane & 15);
  if (rrow >= N) rrow = N - 1;  // clamp: loads safe, stores guarded
  int khalf = lane >> 4;        // 0..3
  f32x4 acc[8];
#pragma unroll
  for (int i = 0; i < 8; ++i) acc[i] = (f32x4){0.f, 0.f, 0.f, 0.f};
  for (int k = 0; k < K; ++k) {
    const unsigned short* Uk = (k == 0) ? xbf : (ubfs + (size_t)(k - 1) * nf);
    const unsigned short* arow = Uk + (size_t)rrow * F128 + khalf * 8;
#pragma unroll
    for (int kk = 0; kk < 4; ++kk) {
      bf16x8 af = *(const bf16x8*)(arow + kk * 32);
      int kstep = k * 4 + kk;
      const unsigned short* bbase = wfrag + (((kstep * 8) * 64 + lane) << 3);
#pragma unroll
      for (int ct = 0; ct < 8; ++ct) {
        bf16x8 bfr = *(const bf16x8*)(bbase + (ct << 9));  // ct*64*8
        acc[ct] = __builtin_amdgcn_mfma_f32_16x16x32_bf16(af, bfr, acc[ct], 0, 0, 0);
      }
    }
  }
#pragma unroll
  for (int ct = 0; ct < 8; ++ct) {
#pragma unroll
    for (int j = 0; j < 4; ++j) {
      int r = n0 + khalf * 4 + j;
      if (r < N) out[(size_t)r * F128 + ct * 16 + (lane & 15)] = fmaxf(acc[ct][j], 0.f);
    }
  }
}

extern "C" void kernel_launch(void* const* d_in, const int* in_sizes, int n_in,
                              void* d_out, int out_size, void* d_ws, size_t ws_size,
                              hipStream_t stream) {
  const float* x = (const float*)d_in[0];
  const float* edge_vals = (const float*)d_in[1];
  const float* weights = (const float*)d_in[2];
  const int* edge_row = (const int*)d_in[3];
  const int* edge_col = (const int*)d_in[4];

  const int N = in_sizes[0] / F128;
  const int E = in_sizes[1];
  const int K = in_sizes[2] / (F128 * F128);
  float* out = (float*)d_out;

  size_t nf = (size_t)N * F128;
  int spmv_blocks = (N + 15) / 16;  // 16 rows per block (4 per wave)
  const int RB = 2048;  // blocks for streaming column-reduce kernels

  unsigned short* wbf = (unsigned short*)d_ws;          // bf16 spmv-output buffer
  unsigned short* xbf = wbf + nf;                       // bf16 shadow of x
  unsigned short* ubfs = xbf + nf;                      // (K-1) bf16 Lanczos shadows
  unsigned short* wfrag = ubfs + (size_t)(K - 1) * nf;
  int wtotal = K * F128 * F128;
  int* row_ptr = (int*)(wfrag + wtotal);
  int* fill = row_ptr + (N + 2);
  int* counts = fill + N;
  int* tmp = counts + N;
  int* partials = tmp + N;        // 256
  int* part_excl = partials + 256;
  int2* edges = (int2*)(part_excl + 256);
  float* dot_part = (float*)(edges + E);                 // spmv_blocks * 128
  float* col_part = dot_part + (size_t)spmv_blocks * F128;  // RB * 128
  float* norms = col_part + (size_t)RB * F128;           // 128
  float* alpha = norms + F128;                           // 8 slots of 128
  float* betasq = alpha + 8 * F128;                      // 8 slots of 128

  hipMemsetAsync(counts, 0, (size_t)N * sizeof(int), stream);

  // CSR build
  int nblk = (N + 1023) / 1024;  // must be <=256
  hist_kernel<<<1024, 256, 0, stream>>>(edge_row, counts, E);
  scan_local_kernel<<<nblk, 1024, 0, stream>>>(counts, tmp, partials, N);
  scan_part_kernel<<<1, 256, 0, stream>>>(partials, part_excl, nblk);
  scan_fin_kernel<<<nblk, 1024, 0, stream>>>(tmp, part_excl, counts, row_ptr, fill, N);
  scatter_kernel<<<2048, 256, 0, stream>>>(edge_row, edge_col, edge_vals, fill, edges, E, N);

  // column sumsq of x + bf16 shadow of x
  colsq_kernel<<<RB, 256, 0, stream>>>(x, xbf, col_part, N);
  reduce_cols_kernel<<<F128, 256, 0, stream>>>(col_part, norms, RB);

  const unsigned short* ubf_prev = xbf;
  const unsigned short* ubf_prev2 = nullptr;
  const float* praw = norms;
  float peps = EPSV;
  const float* p2raw = nullptr;
  float p2eps = 0.f;
  for (int s = 1; s < K; ++s) {
    unsigned short* ubf_out = ubfs + (size_t)(s - 1) * nf;
    float* alph = alpha + (size_t)(s - 1) * F128;
    float* bsq = betasq + (size_t)(s - 1) * F128;

    spmv_dot_kernel<<<spmv_blocks, 256, 0, stream>>>(row_ptr, edges, ubf_prev, praw, peps,
                                                     wbf, dot_part, N);
    reduce_cols_kernel<<<F128, 256, 0, stream>>>(dot_part, alph, spmv_blocks);
    if (s == 1)
      newv_kernel<0><<<RB, 256, 0, stream>>>(wbf, ubf_out, ubf_prev, nullptr, alph, praw, peps,
                                             nullptr, 0.f, col_part, N);
    else
      newv_kernel<1><<<RB, 256, 0, stream>>>(wbf, ubf_out, ubf_prev, ubf_prev2, alph, praw, peps,
                                             p2raw, p2eps, col_part, N);
    reduce_cols_kernel<<<F128, 256, 0, stream>>>(col_part, bsq, RB);

    ubf_prev2 = ubf_prev; p2raw = praw; p2eps = peps;
    ubf_prev = ubf_out;   praw = bsq;   peps = 0.f;
  }

  // fold scales into W (bf16, MFMA frag layout), then one fused MFMA GEMM + relu
  wprep_kernel<<<(wtotal + 255) / 256, 256, 0, stream>>>(weights, norms, betasq, wfrag, wtotal);
  mfma_gemm_kernel<<<(N + 63) / 64, 256, 0, stream>>>(out, xbf, ubfs, nf, wfrag, N, K);
}